// Round 8
// baseline (638.710 us; speedup 1.0000x reference)
//
#include <hip/hip_runtime.h>
#include <cstdint>
#include <math.h>

#define BLK 256
#define NBUK_MAX 1024   // buckets = dst>>8 ; N<=262144

// ---- bf16 pack/unpack helpers ----
__device__ __forceinline__ float bf_lo(unsigned p) { return __uint_as_float(p << 16); }
__device__ __forceinline__ float bf_hi(unsigned p) { return __uint_as_float(p & 0xffff0000u); }
__device__ __forceinline__ unsigned pack2(float a, float b) {
  unsigned ua = __float_as_uint(a), ub = __float_as_uint(b);
  ua = (ua + 0x7fffu + ((ua >> 16) & 1u)) >> 16;        // rne
  ub = (ub + 0x7fffu + ((ub >> 16) & 1u)) >> 16;
  return (ua & 0xffffu) | (ub << 16);
}

typedef _Float16 half8 __attribute__((ext_vector_type(8)));
typedef float f32x4 __attribute__((ext_vector_type(4)));

// ================= generic =================

__global__ void k_zero(int* __restrict__ p, int n) {
  int i = blockIdx.x * blockDim.x + threadIdx.x;
  if (i < n) p[i] = 0;
}

// ================= CSR build via 2-level binning (no global data atomics) =================

__global__ __launch_bounds__(BLK)
void k_bcount(const int* __restrict__ edges, long long E, long long chunk, int nbuk,
              int* __restrict__ bucket_counts) {
  __shared__ int hist[NBUK_MAX];
  for (int i = threadIdx.x; i < nbuk; i += BLK) hist[i] = 0;
  __syncthreads();
  long long beg = (long long)blockIdx.x * chunk;
  long long end = beg + chunk < E ? beg + chunk : E;
  for (long long e = beg + threadIdx.x; e < end; e += BLK)
    atomicAdd(&hist[edges[E + e] >> 8], 1);
  __syncthreads();
  for (int i = threadIdx.x; i < nbuk; i += BLK)
    if (hist[i]) atomicAdd(&bucket_counts[i], hist[i]);
}

__global__ __launch_bounds__(1024)
void k_bscan(const int* __restrict__ bucket_counts, int nbuk,
             int* __restrict__ bucket_start, int* __restrict__ bucket_cursor) {
  __shared__ int tmp[1024];
  int i = threadIdx.x;
  int v = (i < nbuk) ? bucket_counts[i] : 0;
  tmp[i] = v;
  __syncthreads();
  for (int off = 1; off < 1024; off <<= 1) {
    int t = (i >= off) ? tmp[i - off] : 0;
    __syncthreads();
    tmp[i] += t;
    __syncthreads();
  }
  if (i < nbuk) {
    int ex = tmp[i] - v;
    bucket_start[i] = ex;
    bucket_cursor[i] = ex;
  }
  if (i == nbuk - 1) bucket_start[nbuk] = tmp[i];  // sentinel = E
}

__global__ __launch_bounds__(BLK)
void k_bscatter(const int* __restrict__ edges, long long E, long long chunk, int nbuk,
                int* __restrict__ bucket_cursor, int* __restrict__ tmp_out) {
  __shared__ int hist[NBUK_MAX];
  __shared__ int base[NBUK_MAX];
  for (int i = threadIdx.x; i < nbuk; i += BLK) hist[i] = 0;
  __syncthreads();
  long long beg = (long long)blockIdx.x * chunk;
  long long end = beg + chunk < E ? beg + chunk : E;
  for (long long e = beg + threadIdx.x; e < end; e += BLK)
    atomicAdd(&hist[edges[E + e] >> 8], 1);
  __syncthreads();
  for (int i = threadIdx.x; i < nbuk; i += BLK) {
    int c = hist[i];
    base[i] = c ? atomicAdd(&bucket_cursor[i], c) : 0;
    hist[i] = 0;  // reuse as running rank
  }
  __syncthreads();
  for (long long e = beg + threadIdx.x; e < end; e += BLK) {
    int s = edges[e];
    int d = edges[E + e];
    int b = d >> 8;
    int r = atomicAdd(&hist[b], 1);
    tmp_out[base[b] + r] = (s << 8) | (d & 255);  // s < 2^18 -> packed < 2^26
  }
}

__global__ __launch_bounds__(BLK)
void k_bfinal(const int* __restrict__ tmp_in, const int* __restrict__ bucket_start, int n,
              int* __restrict__ row_start, int* __restrict__ counts,
              float* __restrict__ dinv, int* __restrict__ col) {
  __shared__ int cnt[256];
  __shared__ int scan[256];
  __shared__ int cur[256];
  const int b = blockIdx.x, t = threadIdx.x;
  const int seg0 = bucket_start[b], seg1 = bucket_start[b + 1];
  cnt[t] = 0;
  __syncthreads();
  for (int i = seg0 + t; i < seg1; i += BLK) atomicAdd(&cnt[tmp_in[i] & 255], 1);
  __syncthreads();
  int v0 = cnt[t];
  scan[t] = v0;
  __syncthreads();
  for (int off = 1; off < 256; off <<= 1) {
    int x = (t >= off) ? scan[t - off] : 0;
    __syncthreads();
    scan[t] += x;
    __syncthreads();
  }
  int loff = scan[t] - v0;  // exclusive local offset
  int v = b * 256 + t;
  if (v < n) {
    row_start[v] = seg0 + loff;
    counts[v] = v0;
    dinv[v] = rsqrtf((float)v0 + 1.0f);  // +1 self-loop
  }
  cur[t] = loff;
  __syncthreads();
  for (int i = seg0 + t; i < seg1; i += BLK) {
    int p = tmp_in[i];
    int r = atomicAdd(&cur[p & 255], 1);
    col[seg0 + r] = p >> 8;
  }
}

// ================= x fp32 -> fp16 streaming pre-pass =================
// out rows padded to 168 halfs (336B, 16B-aligned) so gemm1h can use aligned
// half8 (dwordx4) A-fragment loads instead of 8 scalar dword + 8 cvt.

__global__ __launch_bounds__(BLK)
void k_cvt16(const float* __restrict__ in, _Float16* __restrict__ out, int n) {
  long long total = (long long)n * 84;   // 84 out-dwords per row (168 halfs)
  for (long long o = blockIdx.x * (long long)BLK + threadIdx.x; o < total;
       o += (long long)gridDim.x * BLK) {
    int r = (int)(o / 84);
    int cd = (int)(o - (long long)r * 84);
    int c = cd * 2;
    const float* src = in + (size_t)r * 165;
    float v0 = (c < 165) ? src[c] : 0.f;
    float v1 = (c + 1 < 165) ? src[c + 1] : 0.f;
    union { _Float16 h[2]; unsigned u; } p;
    p.h[0] = (_Float16)v0;
    p.h[1] = (_Float16)v1;
    *(unsigned*)((char*)out + (size_t)r * 336 + (size_t)c * 2) = p.u;
  }
}

// ================= layer-1 GEMM via fp16 MFMA 16x16x32, bf16 out =================
// fp16-input variant: A-fragments are single aligned half8 loads from the
// padded x16 workspace. Same structure as the verified direct-from-global
// kernel (loads interleaved with MFMAs, 24.6 KB LDS, high occupancy).

__global__ __launch_bounds__(BLK)
void k_gemm1h(const _Float16* __restrict__ x16, const float* __restrict__ W,
              const float* __restrict__ dinv, unsigned* __restrict__ hs1, int n) {
  __shared__ half8 Wl[6 * 4 * 64];   // 24.6 KB
  const int t = threadIdx.x;
  const int lane = t & 63, w = t >> 6;

  // stage W fragments (f16, zero-padded to K=192)
  for (int e = t; e < 12288; e += BLK) {
    int i = e & 7, ln = (e >> 3) & 63, cf = (e >> 9) & 3, ks = e >> 11;
    int k = ks * 32 + ((ln >> 4) << 3) + i;
    int c = (cf << 4) + (ln & 15);
    float v = (k < 165) ? W[k * 64 + c] : 0.f;
    ((_Float16*)Wl)[e] = (_Float16)v;
  }
  __syncthreads();

  const int row0 = blockIdx.x * 256 + w * 64;   // wave's base row
  const int arow = row0 + (lane & 15);          // A row (+ rf*16)
  const int kg = (lane >> 4) << 3;              // k sub-offset: 0,8,16,24

  f32x4 acc[4][4] = {};                          // [rowfrag][colfrag]

  for (int ks = 0; ks < 6; ++ks) {
    half8 b0 = Wl[(ks * 4 + 0) * 64 + lane];
    half8 b1 = Wl[(ks * 4 + 1) * 64 + lane];
    half8 b2 = Wl[(ks * 4 + 2) * 64 + lane];
    half8 b3 = Wl[(ks * 4 + 3) * 64 + lane];
    const int koff = ks * 32 + kg;               // multiple of 8 -> 16B aligned
#pragma unroll
    for (int rf = 0; rf < 4; ++rf) {
      const int r = arow + rf * 16;
      half8 a = {};
      // ks=5: only kg==0 is in-row (halfs 160..167 incl. 3 zero pads);
      // kg!=0 would read past the padded row -> keep zeros.
      if (r < n && (ks < 5 || kg == 0))
        a = *(const half8*)(x16 + (size_t)r * 168 + koff);
      acc[rf][0] = __builtin_amdgcn_mfma_f32_16x16x32_f16(a, b0, acc[rf][0], 0, 0, 0);
      acc[rf][1] = __builtin_amdgcn_mfma_f32_16x16x32_f16(a, b1, acc[rf][1], 0, 0, 0);
      acc[rf][2] = __builtin_amdgcn_mfma_f32_16x16x32_f16(a, b2, acc[rf][2], 0, 0, 0);
      acc[rf][3] = __builtin_amdgcn_mfma_f32_16x16x32_f16(a, b3, acc[rf][3], 0, 0, 0);
    }
  }

  // epilogue: C/D layout col=lane&15, row=(lane>>4)*4+j ; scale by dinv, pack bf16
  const int cq = lane >> 4;
#pragma unroll
  for (int rf = 0; rf < 4; ++rf) {
    const int rb = row0 + rf * 16 + cq * 4;
    float4 dv4 = *(const float4*)&dinv[rb];   // safe: ws arrays follow dinv
    float dvs[4] = {dv4.x, dv4.y, dv4.z, dv4.w};
#pragma unroll
    for (int j = 0; j < 4; ++j) {
      const int r = rb + j;
#pragma unroll
      for (int cf = 0; cf < 4; ++cf) {
        float v = acc[rf][cf][j] * dvs[j];
        float vn = __shfl_xor(v, 1);          // partner holds col+1, same row
        if (!(lane & 1) && r < n)
          hs1[(size_t)r * 32 + ((cf << 4) + (lane & 15)) / 2] = pack2(v, vn);
      }
    }
  }
}

// ================= layer-1 GEMM, fp32-input fallback (ws too small) =================

__global__ __launch_bounds__(BLK)
void k_gemm1(const float* __restrict__ in, const float* __restrict__ W,
             const float* __restrict__ dinv, unsigned* __restrict__ hs1, int n) {
  __shared__ half8 Wl[6 * 4 * 64];   // 24.6 KB
  const int t = threadIdx.x;
  const int lane = t & 63, w = t >> 6;

  for (int e = t; e < 12288; e += BLK) {
    int i = e & 7, ln = (e >> 3) & 63, cf = (e >> 9) & 3, ks = e >> 11;
    int k = ks * 32 + ((ln >> 4) << 3) + i;
    int c = (cf << 4) + (ln & 15);
    float v = (k < 165) ? W[k * 64 + c] : 0.f;
    ((_Float16*)Wl)[e] = (_Float16)v;
  }
  __syncthreads();

  const int row0 = blockIdx.x * 256 + w * 64;
  const int arow = row0 + (lane & 15);
  const int kg = (lane >> 4) << 3;

  f32x4 acc[4][4] = {};

  for (int ks = 0; ks < 6; ++ks) {
    half8 b0 = Wl[(ks * 4 + 0) * 64 + lane];
    half8 b1 = Wl[(ks * 4 + 1) * 64 + lane];
    half8 b2 = Wl[(ks * 4 + 2) * 64 + lane];
    half8 b3 = Wl[(ks * 4 + 3) * 64 + lane];
    const int kbase = ks * 32 + kg;
#pragma unroll
    for (int rf = 0; rf < 4; ++rf) {
      const int r = arow + rf * 16;
      float xv[8] = {0.f, 0.f, 0.f, 0.f, 0.f, 0.f, 0.f, 0.f};
      if (ks < 5) {
        if (r < n) {
          const float* p = in + (size_t)r * 165 + kbase;
#pragma unroll
          for (int i = 0; i < 8; ++i) xv[i] = p[i];
        }
      } else {
        if (r < n && kg == 0) {
          const float* p = in + (size_t)r * 165 + kbase;
#pragma unroll
          for (int i = 0; i < 5; ++i) xv[i] = p[i];
        }
      }
      half8 a;
#pragma unroll
      for (int i = 0; i < 8; ++i) a[i] = (_Float16)xv[i];
      acc[rf][0] = __builtin_amdgcn_mfma_f32_16x16x32_f16(a, b0, acc[rf][0], 0, 0, 0);
      acc[rf][1] = __builtin_amdgcn_mfma_f32_16x16x32_f16(a, b1, acc[rf][1], 0, 0, 0);
      acc[rf][2] = __builtin_amdgcn_mfma_f32_16x16x32_f16(a, b2, acc[rf][2], 0, 0, 0);
      acc[rf][3] = __builtin_amdgcn_mfma_f32_16x16x32_f16(a, b3, acc[rf][3], 0, 0, 0);
    }
  }

  const int cq = lane >> 4;
#pragma unroll
  for (int rf = 0; rf < 4; ++rf) {
    const int rb = row0 + rf * 16 + cq * 4;
    float4 dv4 = *(const float4*)&dinv[rb];
    float dvs[4] = {dv4.x, dv4.y, dv4.z, dv4.w};
#pragma unroll
    for (int j = 0; j < 4; ++j) {
      const int r = rb + j;
#pragma unroll
      for (int cf = 0; cf < 4; ++cf) {
        float v = acc[rf][cf][j] * dvs[j];
        float vn = __shfl_xor(v, 1);
        if (!(lane & 1) && r < n)
          hs1[(size_t)r * 32 + ((cf << 4) + (lane & 15)) / 2] = pack2(v, vn);
      }
    }
  }
}

// ================= fused gather(64,bf16) + bias/ReLU + GEMM 64->16 =================
// wave per node; lane = (sub=lane>>5, u=lane&31); each lane covers channels (2u,2u+1).
// Access shape: 32-lane x 4B contiguous per hs1 row (EMPIRICAL WINNER — do not
// replace with 8-lane x 16B; rounds 1-2 proved that regresses despite fewer insts).
// Deep loop: 8 col + 8 row loads in flight (16 edges/iter) for extra MLP.

#define W2S 33   // padded LDS stride: 4-way bank conflict -> free 2-way

__global__ __launch_bounds__(BLK)
void k_gather64g2(const unsigned* __restrict__ hs1, const int* __restrict__ row_start,
                  const int* __restrict__ counts, const int* __restrict__ col,
                  const float* __restrict__ dinv, const float* __restrict__ b1,
                  const float* __restrict__ W2, unsigned* __restrict__ hs2, int n) {
  __shared__ float W2l[64 * W2S];
  for (int i = threadIdx.x; i < 64 * 16; i += BLK)
    W2l[(i >> 4) * W2S + (i & 15)] = W2[i];
  __syncthreads();

  int wave = threadIdx.x >> 6, lane = threadIdx.x & 63;
  int v = blockIdx.x * 4 + wave;
  if (v >= n) return;
  int sub = lane >> 5, u = lane & 31;
  int beg = row_start[v], cnt = counts[v];

  float a0, a1;
  if (sub == 0) {
    unsigned p = hs1[(size_t)v * 32 + u];  // self-loop
    a0 = bf_lo(p); a1 = bf_hi(p);
  } else {
    a0 = 0.f; a1 = 0.f;
  }

  int e = sub;
  // deep loop: 16 edges/iter, 8 independent col->row chains in flight
  for (; e + 14 < cnt; e += 16) {
    int s0 = col[beg + e];
    int s1 = col[beg + e + 2];
    int s2 = col[beg + e + 4];
    int s3 = col[beg + e + 6];
    int s4 = col[beg + e + 8];
    int s5 = col[beg + e + 10];
    int s6 = col[beg + e + 12];
    int s7 = col[beg + e + 14];
    unsigned p0 = hs1[(size_t)s0 * 32 + u];
    unsigned p1 = hs1[(size_t)s1 * 32 + u];
    unsigned p2 = hs1[(size_t)s2 * 32 + u];
    unsigned p3 = hs1[(size_t)s3 * 32 + u];
    unsigned p4 = hs1[(size_t)s4 * 32 + u];
    unsigned p5 = hs1[(size_t)s5 * 32 + u];
    unsigned p6 = hs1[(size_t)s6 * 32 + u];
    unsigned p7 = hs1[(size_t)s7 * 32 + u];
    a0 += ((bf_lo(p0) + bf_lo(p1)) + (bf_lo(p2) + bf_lo(p3))) +
          ((bf_lo(p4) + bf_lo(p5)) + (bf_lo(p6) + bf_lo(p7)));
    a1 += ((bf_hi(p0) + bf_hi(p1)) + (bf_hi(p2) + bf_hi(p3))) +
          ((bf_hi(p4) + bf_hi(p5)) + (bf_hi(p6) + bf_hi(p7)));
  }
  // mid loop: 8 edges/iter (round-0 body)
  for (; e + 6 < cnt; e += 8) {
    int s0 = col[beg + e];
    int s1 = col[beg + e + 2];
    int s2 = col[beg + e + 4];
    int s3 = col[beg + e + 6];
    unsigned p0 = hs1[(size_t)s0 * 32 + u];
    unsigned p1 = hs1[(size_t)s1 * 32 + u];
    unsigned p2 = hs1[(size_t)s2 * 32 + u];
    unsigned p3 = hs1[(size_t)s3 * 32 + u];
    a0 += (bf_lo(p0) + bf_lo(p1)) + (bf_lo(p2) + bf_lo(p3));
    a1 += (bf_hi(p0) + bf_hi(p1)) + (bf_hi(p2) + bf_hi(p3));
  }
  for (; e < cnt; e += 2) {
    unsigned p = hs1[(size_t)col[beg + e] * 32 + u];
    a0 += bf_lo(p); a1 += bf_hi(p);
  }
  a0 += __shfl_xor(a0, 32);
  a1 += __shfl_xor(a1, 32);

  float dv = dinv[v];
  float2 bb = ((const float2*)b1)[u];
  float r0 = fmaxf(fmaf(a0, dv, bb.x), 0.f);  // relu(agg1[2u])
  float r1 = fmaxf(fmaf(a1, dv, bb.y), 0.f);  // relu(agg1[2u+1])

  // in-wave GEMM2: lane = (o=lane&15, q=lane>>4); k = q*16+i
  int o = lane & 15, q = lane >> 4;
  float part = 0.f;
#pragma unroll
  for (int i = 0; i < 16; i += 2) {
    int k = q * 16 + i;
    float e0 = __shfl(r0, k >> 1);        // channel k (even)
    float e1 = __shfl(r1, k >> 1);        // channel k+1 (odd)
    part = fmaf(e0, W2l[k * W2S + o], part);
    part = fmaf(e1, W2l[(k + 1) * W2S + o], part);
  }
  part += __shfl_xor(part, 16);
  part += __shfl_xor(part, 32);
  float h = part * dv;                     // hs2 channel o (lane<16 valid)
  float hnext = __shfl_xor(h, 1);
  if (lane < 16 && (lane & 1) == 0)
    hs2[(size_t)v * 8 + (o >> 1)] = pack2(h, hnext);
}

// ================= fused gather(16,bf16) + bias/ReLU + GEMM 16->2 =================
// wave per node; lane = (j=lane>>3 edge slot, p=lane&7 -> channels 2p,2p+1)

__global__ __launch_bounds__(BLK)
void k_gather16g3(const unsigned* __restrict__ hs2, const int* __restrict__ row_start,
                  const int* __restrict__ counts, const int* __restrict__ col,
                  const float* __restrict__ dinv, const float* __restrict__ b2,
                  const float* __restrict__ W3, float* __restrict__ hs3, int n) {
  int wave = threadIdx.x >> 6, lane = threadIdx.x & 63;
  int v = blockIdx.x * 4 + wave;
  if (v >= n) return;
  int j = lane >> 3, p = lane & 7;
  int beg = row_start[v], cnt = counts[v];

  float a0 = 0.f, a1 = 0.f;
  int e = j;
  for (; e + 8 < cnt; e += 16) {
    unsigned pk0 = hs2[(size_t)col[beg + e] * 8 + p];
    unsigned pk1 = hs2[(size_t)col[beg + e + 8] * 8 + p];
    a0 += bf_lo(pk0) + bf_lo(pk1);
    a1 += bf_hi(pk0) + bf_hi(pk1);
  }
  if (e < cnt) {
    unsigned pk = hs2[(size_t)col[beg + e] * 8 + p];
    a0 += bf_lo(pk); a1 += bf_hi(pk);
  }
  a0 += __shfl_xor(a0, 8);  a1 += __shfl_xor(a1, 8);
  a0 += __shfl_xor(a0, 16); a1 += __shfl_xor(a1, 16);
  a0 += __shfl_xor(a0, 32); a1 += __shfl_xor(a1, 32);

  unsigned ps = hs2[(size_t)v * 8 + p];  // self-loop
  a0 += bf_lo(ps); a1 += bf_hi(ps);

  float dv = dinv[v];
  float2 bb = ((const float2*)b2)[p];
  float r0 = fmaxf(fmaf(a0, dv, bb.x), 0.f);
  float r1 = fmaxf(fmaf(a1, dv, bb.y), 0.f);

  // GEMM3: out[o] = sum_k relu(agg2[k]) * W3[k][o]; channel 2i->r0@lane i, 2i+1->r1@lane i
  int o = lane & 1;
  float part = 0.f;
#pragma unroll
  for (int i = 0; i < 8; ++i) {
    float e0 = __shfl(r0, i);
    float e1 = __shfl(r1, i);
    part = fmaf(e0, W3[(2 * i) * 2 + o], part);
    part = fmaf(e1, W3[(2 * i + 1) * 2 + o], part);
  }
  if (lane < 2) hs3[(size_t)v * 2 + o] = part * dv;
}

// ================= final gather(2,fp32) + bias + log-softmax =================
// 4 lanes per node: 4 independent col->row chains in flight, quad shuffle-reduce.

__global__ __launch_bounds__(BLK)
void k_gather2_lsm(const float* __restrict__ hs3, const int* __restrict__ row_start,
                   const int* __restrict__ counts, const int* __restrict__ col,
                   const float* __restrict__ dinv, const float* __restrict__ b,
                   float* __restrict__ out, int n) {
  int t = threadIdx.x;
  int v = blockIdx.x * 64 + (t >> 2);
  int sl = t & 3;
  if (v >= n) return;
  const float2* h = (const float2*)hs3;
  int beg = row_start[v], cnt = counts[v];
  float a0 = 0.f, a1 = 0.f;
  int e = sl;
  for (; e + 4 < cnt; e += 8) {
    int c0 = col[beg + e];
    int c1 = col[beg + e + 4];
    float2 m0 = h[c0];
    float2 m1 = h[c1];
    a0 += m0.x + m1.x;
    a1 += m0.y + m1.y;
  }
  if (e < cnt) {
    float2 m = h[col[beg + e]];
    a0 += m.x; a1 += m.y;
  }
  a0 += __shfl_xor(a0, 1); a1 += __shfl_xor(a1, 1);
  a0 += __shfl_xor(a0, 2); a1 += __shfl_xor(a1, 2);
  if (sl == 0) {
    float2 self = h[v];
    a0 += self.x; a1 += self.y;
    float dv = dinv[v];
    a0 = fmaf(a0, dv, b[0]);
    a1 = fmaf(a1, dv, b[1]);
    float m = fmaxf(a0, a1);
    float l = m + logf(expf(a0 - m) + expf(a1 - m));
    ((float2*)out)[v] = make_float2(a0 - l, a1 - l);
  }
}

// ================= launch =================

extern "C" void kernel_launch(void* const* d_in, const int* in_sizes, int n_in,
                              void* d_out, int out_size, void* d_ws, size_t ws_size,
                              hipStream_t stream) {
  const float* x = (const float*)d_in[0];
  const int* edges = (const int*)d_in[1];   // int32
  const float* W1 = (const float*)d_in[2];
  const float* b1 = (const float*)d_in[3];
  const float* W2 = (const float*)d_in[4];
  const float* b2 = (const float*)d_in[5];
  const float* W3 = (const float*)d_in[6];
  const float* b3 = (const float*)d_in[7];
  float* out = (float*)d_out;

  const int N = in_sizes[0] / 165;
  const long long E = in_sizes[1] / 2;
  const int nbuk = (N + 255) >> 8;          // 782

  // workspace layout (16B-aligned chunks)
  char* w = (char*)d_ws;
  int* counts        = (int*)w;  w += (size_t)N * 4;
  int* row_start     = (int*)w;  w += (size_t)N * 4;
  float* dinv        = (float*)w; w += (size_t)N * 4;
  int* bucket_counts = (int*)w;  w += (NBUK_MAX + 4) * 4;
  int* bucket_start  = (int*)w;  w += (NBUK_MAX + 4) * 4;
  int* bucket_cursor = (int*)w;  w += (NBUK_MAX + 4) * 4;
  int* col           = (int*)w;  w += (size_t)E * 4;
  unsigned* hs1      = (unsigned*)w; w += (size_t)N * 32 * 4;   // bf16x2, 128B/row
  unsigned* hs2      = (unsigned*)w; w += (size_t)N * 8 * 4;    // bf16x2, 32B/row
  float* hs3         = (float*)w; w += (size_t)N * 8;            // fp32, 8B/row
  _Float16* x16      = (_Float16*)w;                             // fp16, 336B/row (padded 168)
  size_t need_x16 = (size_t)((char*)x16 - (char*)d_ws) + (size_t)N * 336;
  int use_x16 = (need_x16 <= ws_size);
  int* tmp = (int*)hs1;  // aliases hs1: consumed by k_bfinal before k_gemm1 writes

  const int gN = (N + BLK - 1) / BLK;
  const int gW = (N + 3) / 4;
  const int NB_PART = 256;
  const long long chunk = (E + NB_PART - 1) / NB_PART;

  // ---- CSR build (binning) + dinv ----
  k_zero<<<(nbuk + BLK - 1) / BLK, BLK, 0, stream>>>(bucket_counts, nbuk);
  k_bcount<<<NB_PART, BLK, 0, stream>>>(edges, E, chunk, nbuk, bucket_counts);
  k_bscan<<<1, 1024, 0, stream>>>(bucket_counts, nbuk, bucket_start, bucket_cursor);
  k_bscatter<<<NB_PART, BLK, 0, stream>>>(edges, E, chunk, nbuk, bucket_cursor, tmp);
  k_bfinal<<<nbuk, BLK, 0, stream>>>(tmp, bucket_start, N, row_start, counts, dinv, col);

  // ---- layer 1: 165 -> 64 via fp16 MFMA (bf16 out) ----
  if (use_x16) {
    k_cvt16<<<2048, BLK, 0, stream>>>(x, x16, N);
    k_gemm1h<<<gN, BLK, 0, stream>>>(x16, W1, dinv, hs1, N);
  } else {
    k_gemm1<<<gN, BLK, 0, stream>>>(x, W1, dinv, hs1, N);
  }

  // ---- layer 1 aggregate + layer 2 transform (fused) ----
  k_gather64g2<<<gW, BLK, 0, stream>>>(hs1, row_start, counts, col, dinv, b1, W2, hs2, N);

  // ---- layer 2 aggregate + layer 3 transform (fused) ----
  k_gather16g3<<<gW, BLK, 0, stream>>>(hs2, row_start, counts, col, dinv, b2, W3, hs3, N);

  // ---- layer 3 aggregate + bias + log-softmax ----
  k_gather2_lsm<<<(N + 63) / 64, BLK, 0, stream>>>(hs3, row_start, counts, col, dinv, b3, out, N);
}

// Round 9
// 620.649 us; speedup vs baseline: 1.0291x; 1.0291x over previous
//
#include <hip/hip_runtime.h>
#include <cstdint>
#include <math.h>

#define BLK 256
#define NBUK_MAX 1024   // buckets = dst>>8 ; N<=262144

// ---- bf16 pack/unpack helpers ----
__device__ __forceinline__ float bf_lo(unsigned p) { return __uint_as_float(p << 16); }
__device__ __forceinline__ float bf_hi(unsigned p) { return __uint_as_float(p & 0xffff0000u); }
__device__ __forceinline__ unsigned pack2(float a, float b) {
  unsigned ua = __float_as_uint(a), ub = __float_as_uint(b);
  ua = (ua + 0x7fffu + ((ua >> 16) & 1u)) >> 16;        // rne
  ub = (ub + 0x7fffu + ((ub >> 16) & 1u)) >> 16;
  return (ua & 0xffffu) | (ub << 16);
}

typedef _Float16 half8 __attribute__((ext_vector_type(8)));
typedef float f32x4 __attribute__((ext_vector_type(4)));

// ================= generic =================

__global__ void k_zero(int* __restrict__ p, int n) {
  int i = blockIdx.x * blockDim.x + threadIdx.x;
  if (i < n) p[i] = 0;
}

// ================= CSR build via 2-level binning (no global data atomics) =================

__global__ __launch_bounds__(BLK)
void k_bcount(const int* __restrict__ edges, long long E, long long chunk, int nbuk,
              int* __restrict__ bucket_counts) {
  __shared__ int hist[NBUK_MAX];
  for (int i = threadIdx.x; i < nbuk; i += BLK) hist[i] = 0;
  __syncthreads();
  long long beg = (long long)blockIdx.x * chunk;
  long long end = beg + chunk < E ? beg + chunk : E;
  for (long long e = beg + threadIdx.x; e < end; e += BLK)
    atomicAdd(&hist[edges[E + e] >> 8], 1);
  __syncthreads();
  for (int i = threadIdx.x; i < nbuk; i += BLK)
    if (hist[i]) atomicAdd(&bucket_counts[i], hist[i]);
}

__global__ __launch_bounds__(1024)
void k_bscan(const int* __restrict__ bucket_counts, int nbuk,
             int* __restrict__ bucket_start, int* __restrict__ bucket_cursor) {
  __shared__ int tmp[1024];
  int i = threadIdx.x;
  int v = (i < nbuk) ? bucket_counts[i] : 0;
  tmp[i] = v;
  __syncthreads();
  for (int off = 1; off < 1024; off <<= 1) {
    int t = (i >= off) ? tmp[i - off] : 0;
    __syncthreads();
    tmp[i] += t;
    __syncthreads();
  }
  if (i < nbuk) {
    int ex = tmp[i] - v;
    bucket_start[i] = ex;
    bucket_cursor[i] = ex;
  }
  if (i == nbuk - 1) bucket_start[nbuk] = tmp[i];  // sentinel = E
}

__global__ __launch_bounds__(BLK)
void k_bscatter(const int* __restrict__ edges, long long E, long long chunk, int nbuk,
                int* __restrict__ bucket_cursor, int* __restrict__ tmp_out) {
  __shared__ int hist[NBUK_MAX];
  __shared__ int base[NBUK_MAX];
  for (int i = threadIdx.x; i < nbuk; i += BLK) hist[i] = 0;
  __syncthreads();
  long long beg = (long long)blockIdx.x * chunk;
  long long end = beg + chunk < E ? beg + chunk : E;
  for (long long e = beg + threadIdx.x; e < end; e += BLK)
    atomicAdd(&hist[edges[E + e] >> 8], 1);
  __syncthreads();
  for (int i = threadIdx.x; i < nbuk; i += BLK) {
    int c = hist[i];
    base[i] = c ? atomicAdd(&bucket_cursor[i], c) : 0;
    hist[i] = 0;  // reuse as running rank
  }
  __syncthreads();
  for (long long e = beg + threadIdx.x; e < end; e += BLK) {
    int s = edges[e];
    int d = edges[E + e];
    int b = d >> 8;
    int r = atomicAdd(&hist[b], 1);
    tmp_out[base[b] + r] = (s << 8) | (d & 255);  // s < 2^18 -> packed < 2^26
  }
}

__global__ __launch_bounds__(BLK)
void k_bfinal(const int* __restrict__ tmp_in, const int* __restrict__ bucket_start, int n,
              int* __restrict__ row_start, int* __restrict__ counts,
              float* __restrict__ dinv, int* __restrict__ col) {
  __shared__ int cnt[256];
  __shared__ int scan[256];
  __shared__ int cur[256];
  const int b = blockIdx.x, t = threadIdx.x;
  const int seg0 = bucket_start[b], seg1 = bucket_start[b + 1];
  cnt[t] = 0;
  __syncthreads();
  for (int i = seg0 + t; i < seg1; i += BLK) atomicAdd(&cnt[tmp_in[i] & 255], 1);
  __syncthreads();
  int v0 = cnt[t];
  scan[t] = v0;
  __syncthreads();
  for (int off = 1; off < 256; off <<= 1) {
    int x = (t >= off) ? scan[t - off] : 0;
    __syncthreads();
    scan[t] += x;
    __syncthreads();
  }
  int loff = scan[t] - v0;  // exclusive local offset
  int v = b * 256 + t;
  if (v < n) {
    row_start[v] = seg0 + loff;
    counts[v] = v0;
    dinv[v] = rsqrtf((float)v0 + 1.0f);  // +1 self-loop
  }
  cur[t] = loff;
  __syncthreads();
  for (int i = seg0 + t; i < seg1; i += BLK) {
    int p = tmp_in[i];
    int r = atomicAdd(&cur[p & 255], 1);
    col[seg0 + r] = p >> 8;
  }
}

// ================= layer-1 GEMM via fp16 MFMA 16x16x32, bf16 out =================
// Direct-from-global A-fragments interleaved with MFMAs (EMPIRICAL WINNER for
// this kernel — round-4's phase-serial LDS staging regressed 2.2x; round-7's
// cvt16+aligned-load split cost more than it saved). W1 staged once into LDS.

__global__ __launch_bounds__(BLK)
void k_gemm1(const float* __restrict__ in, const float* __restrict__ W,
             const float* __restrict__ dinv, unsigned* __restrict__ hs1, int n) {
  __shared__ half8 Wl[6 * 4 * 64];   // 24.6 KB
  const int t = threadIdx.x;
  const int lane = t & 63, w = t >> 6;

  // stage W fragments (f16, zero-padded to K=192)
  for (int e = t; e < 12288; e += BLK) {
    int i = e & 7, ln = (e >> 3) & 63, cf = (e >> 9) & 3, ks = e >> 11;
    int k = ks * 32 + ((ln >> 4) << 3) + i;
    int c = (cf << 4) + (ln & 15);
    float v = (k < 165) ? W[k * 64 + c] : 0.f;
    ((_Float16*)Wl)[e] = (_Float16)v;
  }
  __syncthreads();

  const int row0 = blockIdx.x * 256 + w * 64;   // wave's base row
  const int arow = row0 + (lane & 15);          // A row (+ rf*16)
  const int kg = (lane >> 4) << 3;              // k sub-offset: 0,8,16,24

  f32x4 acc[4][4] = {};                          // [rowfrag][colfrag]

  for (int ks = 0; ks < 6; ++ks) {
    half8 b0 = Wl[(ks * 4 + 0) * 64 + lane];
    half8 b1 = Wl[(ks * 4 + 1) * 64 + lane];
    half8 b2 = Wl[(ks * 4 + 2) * 64 + lane];
    half8 b3 = Wl[(ks * 4 + 3) * 64 + lane];
    const int kbase = ks * 32 + kg;
#pragma unroll
    for (int rf = 0; rf < 4; ++rf) {
      const int r = arow + rf * 16;
      float xv[8] = {0.f, 0.f, 0.f, 0.f, 0.f, 0.f, 0.f, 0.f};
      if (ks < 5) {
        if (r < n) {
          const float* p = in + (size_t)r * 165 + kbase;
#pragma unroll
          for (int i = 0; i < 8; ++i) xv[i] = p[i];
        }
      } else {
        if (r < n && kg == 0) {
          const float* p = in + (size_t)r * 165 + kbase;
#pragma unroll
          for (int i = 0; i < 5; ++i) xv[i] = p[i];
        }
      }
      half8 a;
#pragma unroll
      for (int i = 0; i < 8; ++i) a[i] = (_Float16)xv[i];
      acc[rf][0] = __builtin_amdgcn_mfma_f32_16x16x32_f16(a, b0, acc[rf][0], 0, 0, 0);
      acc[rf][1] = __builtin_amdgcn_mfma_f32_16x16x32_f16(a, b1, acc[rf][1], 0, 0, 0);
      acc[rf][2] = __builtin_amdgcn_mfma_f32_16x16x32_f16(a, b2, acc[rf][2], 0, 0, 0);
      acc[rf][3] = __builtin_amdgcn_mfma_f32_16x16x32_f16(a, b3, acc[rf][3], 0, 0, 0);
    }
  }

  // epilogue: C/D layout col=lane&15, row=(lane>>4)*4+j ; scale by dinv, pack bf16
  const int cq = lane >> 4;
#pragma unroll
  for (int rf = 0; rf < 4; ++rf) {
    const int rb = row0 + rf * 16 + cq * 4;
    float4 dv4 = *(const float4*)&dinv[rb];   // safe: ws arrays follow dinv
    float dvs[4] = {dv4.x, dv4.y, dv4.z, dv4.w};
#pragma unroll
    for (int j = 0; j < 4; ++j) {
      const int r = rb + j;
#pragma unroll
      for (int cf = 0; cf < 4; ++cf) {
        float v = acc[rf][cf][j] * dvs[j];
        float vn = __shfl_xor(v, 1);          // partner holds col+1, same row
        if (!(lane & 1) && r < n)
          hs1[(size_t)r * 32 + ((cf << 4) + (lane & 15)) / 2] = pack2(v, vn);
      }
    }
  }
}

// ================= fused gather(64,bf16) + bias/ReLU + GEMM 64->16 =================
// wave per node; lane = (sub=lane>>5, u=lane&31); each lane covers channels (2u,2u+1).
// Access shape: 32-lane x 4B contiguous per hs1 row (EMPIRICAL WINNER — do not
// replace with 8-lane x 16B; rounds 1-2 proved that regresses despite fewer insts).
// Deep loop: 8 col + 8 row loads in flight (16 edges/iter) for extra MLP.

#define W2S 33   // padded LDS stride: 4-way bank conflict -> free 2-way

__global__ __launch_bounds__(BLK)
void k_gather64g2(const unsigned* __restrict__ hs1, const int* __restrict__ row_start,
                  const int* __restrict__ counts, const int* __restrict__ col,
                  const float* __restrict__ dinv, const float* __restrict__ b1,
                  const float* __restrict__ W2, unsigned* __restrict__ hs2, int n) {
  __shared__ float W2l[64 * W2S];
  for (int i = threadIdx.x; i < 64 * 16; i += BLK)
    W2l[(i >> 4) * W2S + (i & 15)] = W2[i];
  __syncthreads();

  int wave = threadIdx.x >> 6, lane = threadIdx.x & 63;
  int v = blockIdx.x * 4 + wave;
  if (v >= n) return;
  int sub = lane >> 5, u = lane & 31;
  int beg = row_start[v], cnt = counts[v];

  float a0, a1;
  if (sub == 0) {
    unsigned p = hs1[(size_t)v * 32 + u];  // self-loop
    a0 = bf_lo(p); a1 = bf_hi(p);
  } else {
    a0 = 0.f; a1 = 0.f;
  }

  int e = sub;
  // deep loop: 16 edges/iter, 8 independent col->row chains in flight
  for (; e + 14 < cnt; e += 16) {
    int s0 = col[beg + e];
    int s1 = col[beg + e + 2];
    int s2 = col[beg + e + 4];
    int s3 = col[beg + e + 6];
    int s4 = col[beg + e + 8];
    int s5 = col[beg + e + 10];
    int s6 = col[beg + e + 12];
    int s7 = col[beg + e + 14];
    unsigned p0 = hs1[(size_t)s0 * 32 + u];
    unsigned p1 = hs1[(size_t)s1 * 32 + u];
    unsigned p2 = hs1[(size_t)s2 * 32 + u];
    unsigned p3 = hs1[(size_t)s3 * 32 + u];
    unsigned p4 = hs1[(size_t)s4 * 32 + u];
    unsigned p5 = hs1[(size_t)s5 * 32 + u];
    unsigned p6 = hs1[(size_t)s6 * 32 + u];
    unsigned p7 = hs1[(size_t)s7 * 32 + u];
    a0 += ((bf_lo(p0) + bf_lo(p1)) + (bf_lo(p2) + bf_lo(p3))) +
          ((bf_lo(p4) + bf_lo(p5)) + (bf_lo(p6) + bf_lo(p7)));
    a1 += ((bf_hi(p0) + bf_hi(p1)) + (bf_hi(p2) + bf_hi(p3))) +
          ((bf_hi(p4) + bf_hi(p5)) + (bf_hi(p6) + bf_hi(p7)));
  }
  // mid loop: 8 edges/iter (round-0 body)
  for (; e + 6 < cnt; e += 8) {
    int s0 = col[beg + e];
    int s1 = col[beg + e + 2];
    int s2 = col[beg + e + 4];
    int s3 = col[beg + e + 6];
    unsigned p0 = hs1[(size_t)s0 * 32 + u];
    unsigned p1 = hs1[(size_t)s1 * 32 + u];
    unsigned p2 = hs1[(size_t)s2 * 32 + u];
    unsigned p3 = hs1[(size_t)s3 * 32 + u];
    a0 += (bf_lo(p0) + bf_lo(p1)) + (bf_lo(p2) + bf_lo(p3));
    a1 += (bf_hi(p0) + bf_hi(p1)) + (bf_hi(p2) + bf_hi(p3));
  }
  for (; e < cnt; e += 2) {
    unsigned p = hs1[(size_t)col[beg + e] * 32 + u];
    a0 += bf_lo(p); a1 += bf_hi(p);
  }
  a0 += __shfl_xor(a0, 32);
  a1 += __shfl_xor(a1, 32);

  float dv = dinv[v];
  float2 bb = ((const float2*)b1)[u];
  float r0 = fmaxf(fmaf(a0, dv, bb.x), 0.f);  // relu(agg1[2u])
  float r1 = fmaxf(fmaf(a1, dv, bb.y), 0.f);  // relu(agg1[2u+1])

  // in-wave GEMM2: lane = (o=lane&15, q=lane>>4); k = q*16+i
  int o = lane & 15, q = lane >> 4;
  float part = 0.f;
#pragma unroll
  for (int i = 0; i < 16; i += 2) {
    int k = q * 16 + i;
    float e0 = __shfl(r0, k >> 1);        // channel k (even)
    float e1 = __shfl(r1, k >> 1);        // channel k+1 (odd)
    part = fmaf(e0, W2l[k * W2S + o], part);
    part = fmaf(e1, W2l[(k + 1) * W2S + o], part);
  }
  part += __shfl_xor(part, 16);
  part += __shfl_xor(part, 32);
  float h = part * dv;                     // hs2 channel o (lane<16 valid)
  float hnext = __shfl_xor(h, 1);
  if (lane < 16 && (lane & 1) == 0)
    hs2[(size_t)v * 8 + (o >> 1)] = pack2(h, hnext);
}

// ================= fused gather(16,bf16) + bias/ReLU + GEMM 16->2 =================
// wave per node; lane = (j=lane>>3 edge slot, p=lane&7 -> channels 2p,2p+1)

__global__ __launch_bounds__(BLK)
void k_gather16g3(const unsigned* __restrict__ hs2, const int* __restrict__ row_start,
                  const int* __restrict__ counts, const int* __restrict__ col,
                  const float* __restrict__ dinv, const float* __restrict__ b2,
                  const float* __restrict__ W3, float* __restrict__ hs3, int n) {
  int wave = threadIdx.x >> 6, lane = threadIdx.x & 63;
  int v = blockIdx.x * 4 + wave;
  if (v >= n) return;
  int j = lane >> 3, p = lane & 7;
  int beg = row_start[v], cnt = counts[v];

  float a0 = 0.f, a1 = 0.f;
  int e = j;
  for (; e + 8 < cnt; e += 16) {
    unsigned pk0 = hs2[(size_t)col[beg + e] * 8 + p];
    unsigned pk1 = hs2[(size_t)col[beg + e + 8] * 8 + p];
    a0 += bf_lo(pk0) + bf_lo(pk1);
    a1 += bf_hi(pk0) + bf_hi(pk1);
  }
  if (e < cnt) {
    unsigned pk = hs2[(size_t)col[beg + e] * 8 + p];
    a0 += bf_lo(pk); a1 += bf_hi(pk);
  }
  a0 += __shfl_xor(a0, 8);  a1 += __shfl_xor(a1, 8);
  a0 += __shfl_xor(a0, 16); a1 += __shfl_xor(a1, 16);
  a0 += __shfl_xor(a0, 32); a1 += __shfl_xor(a1, 32);

  unsigned ps = hs2[(size_t)v * 8 + p];  // self-loop
  a0 += bf_lo(ps); a1 += bf_hi(ps);

  float dv = dinv[v];
  float2 bb = ((const float2*)b2)[p];
  float r0 = fmaxf(fmaf(a0, dv, bb.x), 0.f);
  float r1 = fmaxf(fmaf(a1, dv, bb.y), 0.f);

  // GEMM3: out[o] = sum_k relu(agg2[k]) * W3[k][o]; channel 2i->r0@lane i, 2i+1->r1@lane i
  int o = lane & 1;
  float part = 0.f;
#pragma unroll
  for (int i = 0; i < 8; ++i) {
    float e0 = __shfl(r0, i);
    float e1 = __shfl(r1, i);
    part = fmaf(e0, W3[(2 * i) * 2 + o], part);
    part = fmaf(e1, W3[(2 * i + 1) * 2 + o], part);
  }
  if (lane < 2) hs3[(size_t)v * 2 + o] = part * dv;
}

// ================= final gather(2,fp32) + bias + log-softmax =================
// 4 lanes per node: 4 independent col->row chains in flight, quad shuffle-reduce.

__global__ __launch_bounds__(BLK)
void k_gather2_lsm(const float* __restrict__ hs3, const int* __restrict__ row_start,
                   const int* __restrict__ counts, const int* __restrict__ col,
                   const float* __restrict__ dinv, const float* __restrict__ b,
                   float* __restrict__ out, int n) {
  int t = threadIdx.x;
  int v = blockIdx.x * 64 + (t >> 2);
  int sl = t & 3;
  if (v >= n) return;
  const float2* h = (const float2*)hs3;
  int beg = row_start[v], cnt = counts[v];
  float a0 = 0.f, a1 = 0.f;
  int e = sl;
  for (; e + 4 < cnt; e += 8) {
    int c0 = col[beg + e];
    int c1 = col[beg + e + 4];
    float2 m0 = h[c0];
    float2 m1 = h[c1];
    a0 += m0.x + m1.x;
    a1 += m0.y + m1.y;
  }
  if (e < cnt) {
    float2 m = h[col[beg + e]];
    a0 += m.x; a1 += m.y;
  }
  a0 += __shfl_xor(a0, 1); a1 += __shfl_xor(a1, 1);
  a0 += __shfl_xor(a0, 2); a1 += __shfl_xor(a1, 2);
  if (sl == 0) {
    float2 self = h[v];
    a0 += self.x; a1 += self.y;
    float dv = dinv[v];
    a0 = fmaf(a0, dv, b[0]);
    a1 = fmaf(a1, dv, b[1]);
    float m = fmaxf(a0, a1);
    float l = m + logf(expf(a0 - m) + expf(a1 - m));
    ((float2*)out)[v] = make_float2(a0 - l, a1 - l);
  }
}

// ================= launch =================

extern "C" void kernel_launch(void* const* d_in, const int* in_sizes, int n_in,
                              void* d_out, int out_size, void* d_ws, size_t ws_size,
                              hipStream_t stream) {
  const float* x = (const float*)d_in[0];
  const int* edges = (const int*)d_in[1];   // int32
  const float* W1 = (const float*)d_in[2];
  const float* b1 = (const float*)d_in[3];
  const float* W2 = (const float*)d_in[4];
  const float* b2 = (const float*)d_in[5];
  const float* W3 = (const float*)d_in[6];
  const float* b3 = (const float*)d_in[7];
  float* out = (float*)d_out;

  const int N = in_sizes[0] / 165;
  const long long E = in_sizes[1] / 2;
  const int nbuk = (N + 255) >> 8;          // 782

  // workspace layout (16B-aligned chunks)
  char* w = (char*)d_ws;
  int* counts        = (int*)w;  w += (size_t)N * 4;
  int* row_start     = (int*)w;  w += (size_t)N * 4;
  float* dinv        = (float*)w; w += (size_t)N * 4;
  int* bucket_counts = (int*)w;  w += (NBUK_MAX + 4) * 4;
  int* bucket_start  = (int*)w;  w += (NBUK_MAX + 4) * 4;
  int* bucket_cursor = (int*)w;  w += (NBUK_MAX + 4) * 4;
  int* col           = (int*)w;  w += (size_t)E * 4;
  unsigned* hs1      = (unsigned*)w; w += (size_t)N * 32 * 4;   // bf16x2, 128B/row
  unsigned* hs2      = (unsigned*)w; w += (size_t)N * 8 * 4;    // bf16x2, 32B/row
  float* hs3         = (float*)w;                                // fp32, 8B/row
  int* tmp = (int*)hs1;  // aliases hs1: consumed by k_bfinal before k_gemm1 writes

  const int gN = (N + BLK - 1) / BLK;
  const int gW = (N + 3) / 4;
  const int NB_PART = 256;
  const long long chunk = (E + NB_PART - 1) / NB_PART;

  // ---- CSR build (binning) + dinv ----
  k_zero<<<(nbuk + BLK - 1) / BLK, BLK, 0, stream>>>(bucket_counts, nbuk);
  k_bcount<<<NB_PART, BLK, 0, stream>>>(edges, E, chunk, nbuk, bucket_counts);
  k_bscan<<<1, 1024, 0, stream>>>(bucket_counts, nbuk, bucket_start, bucket_cursor);
  k_bscatter<<<NB_PART, BLK, 0, stream>>>(edges, E, chunk, nbuk, bucket_cursor, tmp);
  k_bfinal<<<nbuk, BLK, 0, stream>>>(tmp, bucket_start, N, row_start, counts, dinv, col);

  // ---- layer 1: 165 -> 64 via fp16 MFMA (bf16 out) ----
  k_gemm1<<<gN, BLK, 0, stream>>>(x, W1, dinv, hs1, N);

  // ---- layer 1 aggregate + layer 2 transform (fused) ----
  k_gather64g2<<<gW, BLK, 0, stream>>>(hs1, row_start, counts, col, dinv, b1, W2, hs2, N);

  // ---- layer 2 aggregate + layer 3 transform (fused) ----
  k_gather16g3<<<gW, BLK, 0, stream>>>(hs2, row_start, counts, col, dinv, b2, W3, hs3, N);

  // ---- layer 3 aggregate + bias + log-softmax ----
  k_gather2_lsm<<<(N + 63) / 64, BLK, 0, stream>>>(hs3, row_start, counts, col, dinv, b3, out, N);
}

// Round 10
// 611.847 us; speedup vs baseline: 1.0439x; 1.0144x over previous
//
#include <hip/hip_runtime.h>
#include <cstdint>
#include <math.h>

#define BLK 256
#define NBUK_MAX 1024   // buckets = dst>>8 ; N<=262144

// ---- bf16 pack/unpack helpers ----
__device__ __forceinline__ float bf_lo(unsigned p) { return __uint_as_float(p << 16); }
__device__ __forceinline__ float bf_hi(unsigned p) { return __uint_as_float(p & 0xffff0000u); }
__device__ __forceinline__ unsigned pack2(float a, float b) {
  unsigned ua = __float_as_uint(a), ub = __float_as_uint(b);
  ua = (ua + 0x7fffu + ((ua >> 16) & 1u)) >> 16;        // rne
  ub = (ub + 0x7fffu + ((ub >> 16) & 1u)) >> 16;
  return (ua & 0xffffu) | (ub << 16);
}

typedef _Float16 half8 __attribute__((ext_vector_type(8)));
typedef float f32x4 __attribute__((ext_vector_type(4)));

// ================= generic =================

__global__ void k_zero(int* __restrict__ p, int n) {
  int i = blockIdx.x * blockDim.x + threadIdx.x;
  if (i < n) p[i] = 0;
}

// ================= CSR build via 2-level binning (no global data atomics) =================

__global__ __launch_bounds__(BLK)
void k_bcount(const int* __restrict__ edges, long long E, long long chunk, int nbuk,
              int* __restrict__ bucket_counts) {
  __shared__ int hist[NBUK_MAX];
  for (int i = threadIdx.x; i < nbuk; i += BLK) hist[i] = 0;
  __syncthreads();
  long long beg = (long long)blockIdx.x * chunk;
  long long end = beg + chunk < E ? beg + chunk : E;
  for (long long e = beg + threadIdx.x; e < end; e += BLK)
    atomicAdd(&hist[edges[E + e] >> 8], 1);
  __syncthreads();
  for (int i = threadIdx.x; i < nbuk; i += BLK)
    if (hist[i]) atomicAdd(&bucket_counts[i], hist[i]);
}

__global__ __launch_bounds__(1024)
void k_bscan(const int* __restrict__ bucket_counts, int nbuk,
             int* __restrict__ bucket_start, int* __restrict__ bucket_cursor) {
  __shared__ int tmp[1024];
  int i = threadIdx.x;
  int v = (i < nbuk) ? bucket_counts[i] : 0;
  tmp[i] = v;
  __syncthreads();
  for (int off = 1; off < 1024; off <<= 1) {
    int t = (i >= off) ? tmp[i - off] : 0;
    __syncthreads();
    tmp[i] += t;
    __syncthreads();
  }
  if (i < nbuk) {
    int ex = tmp[i] - v;
    bucket_start[i] = ex;
    bucket_cursor[i] = ex;
  }
  if (i == nbuk - 1) bucket_start[nbuk] = tmp[i];  // sentinel = E
}

__global__ __launch_bounds__(BLK)
void k_bscatter(const int* __restrict__ edges, long long E, long long chunk, int nbuk,
                int* __restrict__ bucket_cursor, int* __restrict__ tmp_out) {
  __shared__ int hist[NBUK_MAX];
  __shared__ int base[NBUK_MAX];
  for (int i = threadIdx.x; i < nbuk; i += BLK) hist[i] = 0;
  __syncthreads();
  long long beg = (long long)blockIdx.x * chunk;
  long long end = beg + chunk < E ? beg + chunk : E;
  for (long long e = beg + threadIdx.x; e < end; e += BLK)
    atomicAdd(&hist[edges[E + e] >> 8], 1);
  __syncthreads();
  for (int i = threadIdx.x; i < nbuk; i += BLK) {
    int c = hist[i];
    base[i] = c ? atomicAdd(&bucket_cursor[i], c) : 0;
    hist[i] = 0;  // reuse as running rank
  }
  __syncthreads();
  for (long long e = beg + threadIdx.x; e < end; e += BLK) {
    int s = edges[e];
    int d = edges[E + e];
    int b = d >> 8;
    int r = atomicAdd(&hist[b], 1);
    tmp_out[base[b] + r] = (s << 8) | (d & 255);  // s < 2^18 -> packed < 2^26
  }
}

__global__ __launch_bounds__(BLK)
void k_bfinal(const int* __restrict__ tmp_in, const int* __restrict__ bucket_start, int n,
              int* __restrict__ row_start, int* __restrict__ counts,
              float* __restrict__ dinv, int* __restrict__ col) {
  __shared__ int cnt[256];
  __shared__ int scan[256];
  __shared__ int cur[256];
  const int b = blockIdx.x, t = threadIdx.x;
  const int seg0 = bucket_start[b], seg1 = bucket_start[b + 1];
  cnt[t] = 0;
  __syncthreads();
  for (int i = seg0 + t; i < seg1; i += BLK) atomicAdd(&cnt[tmp_in[i] & 255], 1);
  __syncthreads();
  int v0 = cnt[t];
  scan[t] = v0;
  __syncthreads();
  for (int off = 1; off < 256; off <<= 1) {
    int x = (t >= off) ? scan[t - off] : 0;
    __syncthreads();
    scan[t] += x;
    __syncthreads();
  }
  int loff = scan[t] - v0;  // exclusive local offset
  int v = b * 256 + t;
  if (v < n) {
    row_start[v] = seg0 + loff;
    counts[v] = v0;
    dinv[v] = rsqrtf((float)v0 + 1.0f);  // +1 self-loop
  }
  cur[t] = loff;
  __syncthreads();
  for (int i = seg0 + t; i < seg1; i += BLK) {
    int p = tmp_in[i];
    int r = atomicAdd(&cur[p & 255], 1);
    col[seg0 + r] = p >> 8;
  }
}

// ================= layer-1 GEMM via fp16 MFMA 16x16x32, bf16 out =================
// Direct-from-global A-fragments interleaved with MFMAs (EMPIRICAL WINNER:
// round-4 staging -2.2x, round-7 cvt-split -20us). This round: wave covers
// 32 rows (acc[2][4], -32 VGPR) -> ~5 waves/SIMD vs 3, to hide the exposed
// load->MFMA latency (round-7 showed the kernel is latency- not issue-bound).

#define G1R 128   // rows per block (4 waves x 32 rows)

__global__ __launch_bounds__(BLK)
void k_gemm1(const float* __restrict__ in, const float* __restrict__ W,
             const float* __restrict__ dinv, unsigned* __restrict__ hs1, int n) {
  __shared__ half8 Wl[6 * 4 * 64];   // 24.6 KB
  const int t = threadIdx.x;
  const int lane = t & 63, w = t >> 6;

  // stage W fragments (f16, zero-padded to K=192)
  for (int e = t; e < 12288; e += BLK) {
    int i = e & 7, ln = (e >> 3) & 63, cf = (e >> 9) & 3, ks = e >> 11;
    int k = ks * 32 + ((ln >> 4) << 3) + i;
    int c = (cf << 4) + (ln & 15);
    float v = (k < 165) ? W[k * 64 + c] : 0.f;
    ((_Float16*)Wl)[e] = (_Float16)v;
  }
  __syncthreads();

  const int row0 = blockIdx.x * G1R + w * 32;   // wave's base row
  const int arow = row0 + (lane & 15);          // A row (+ rf*16)
  const int kg = (lane >> 4) << 3;              // k sub-offset: 0,8,16,24

  f32x4 acc[2][4] = {};                          // [rowfrag][colfrag]

  for (int ks = 0; ks < 6; ++ks) {
    half8 b0 = Wl[(ks * 4 + 0) * 64 + lane];
    half8 b1 = Wl[(ks * 4 + 1) * 64 + lane];
    half8 b2 = Wl[(ks * 4 + 2) * 64 + lane];
    half8 b3 = Wl[(ks * 4 + 3) * 64 + lane];
    const int kbase = ks * 32 + kg;
#pragma unroll
    for (int rf = 0; rf < 2; ++rf) {
      const int r = arow + rf * 16;
      float xv[8] = {0.f, 0.f, 0.f, 0.f, 0.f, 0.f, 0.f, 0.f};
      if (ks < 5) {
        if (r < n) {
          const float* p = in + (size_t)r * 165 + kbase;
#pragma unroll
          for (int i = 0; i < 8; ++i) xv[i] = p[i];
        }
      } else {
        if (r < n && kg == 0) {
          const float* p = in + (size_t)r * 165 + kbase;
#pragma unroll
          for (int i = 0; i < 5; ++i) xv[i] = p[i];
        }
      }
      half8 a;
#pragma unroll
      for (int i = 0; i < 8; ++i) a[i] = (_Float16)xv[i];
      acc[rf][0] = __builtin_amdgcn_mfma_f32_16x16x32_f16(a, b0, acc[rf][0], 0, 0, 0);
      acc[rf][1] = __builtin_amdgcn_mfma_f32_16x16x32_f16(a, b1, acc[rf][1], 0, 0, 0);
      acc[rf][2] = __builtin_amdgcn_mfma_f32_16x16x32_f16(a, b2, acc[rf][2], 0, 0, 0);
      acc[rf][3] = __builtin_amdgcn_mfma_f32_16x16x32_f16(a, b3, acc[rf][3], 0, 0, 0);
    }
  }

  // epilogue: C/D layout col=lane&15, row=(lane>>4)*4+j ; scale by dinv, pack bf16
  const int cq = lane >> 4;
#pragma unroll
  for (int rf = 0; rf < 2; ++rf) {
    const int rb = row0 + rf * 16 + cq * 4;
    float4 dv4 = *(const float4*)&dinv[rb];   // safe: ws arrays follow dinv
    float dvs[4] = {dv4.x, dv4.y, dv4.z, dv4.w};
#pragma unroll
    for (int j = 0; j < 4; ++j) {
      const int r = rb + j;
#pragma unroll
      for (int cf = 0; cf < 4; ++cf) {
        float v = acc[rf][cf][j] * dvs[j];
        float vn = __shfl_xor(v, 1);          // partner holds col+1, same row
        if (!(lane & 1) && r < n)
          hs1[(size_t)r * 32 + ((cf << 4) + (lane & 15)) / 2] = pack2(v, vn);
      }
    }
  }
}

// ================= fused gather(64,bf16) + bias/ReLU + GEMM 64->16 =================
// wave per node; lane = (sub=lane>>5, u=lane&31); each lane covers channels (2u,2u+1).
// Access shape: 32-lane x 4B contiguous per hs1 row (EMPIRICAL WINNER — do not
// replace with 8-lane x 16B; rounds 1-2 proved that regresses despite fewer insts).
// Deep loop: 8 col + 8 row loads in flight (16 edges/iter) for extra MLP.

#define W2S 33   // padded LDS stride: 4-way bank conflict -> free 2-way

__global__ __launch_bounds__(BLK)
void k_gather64g2(const unsigned* __restrict__ hs1, const int* __restrict__ row_start,
                  const int* __restrict__ counts, const int* __restrict__ col,
                  const float* __restrict__ dinv, const float* __restrict__ b1,
                  const float* __restrict__ W2, unsigned* __restrict__ hs2, int n) {
  __shared__ float W2l[64 * W2S];
  for (int i = threadIdx.x; i < 64 * 16; i += BLK)
    W2l[(i >> 4) * W2S + (i & 15)] = W2[i];
  __syncthreads();

  int wave = threadIdx.x >> 6, lane = threadIdx.x & 63;
  int v = blockIdx.x * 4 + wave;
  if (v >= n) return;
  int sub = lane >> 5, u = lane & 31;
  int beg = row_start[v], cnt = counts[v];

  float a0, a1;
  if (sub == 0) {
    unsigned p = hs1[(size_t)v * 32 + u];  // self-loop
    a0 = bf_lo(p); a1 = bf_hi(p);
  } else {
    a0 = 0.f; a1 = 0.f;
  }

  int e = sub;
  // deep loop: 16 edges/iter, 8 independent col->row chains in flight
  for (; e + 14 < cnt; e += 16) {
    int s0 = col[beg + e];
    int s1 = col[beg + e + 2];
    int s2 = col[beg + e + 4];
    int s3 = col[beg + e + 6];
    int s4 = col[beg + e + 8];
    int s5 = col[beg + e + 10];
    int s6 = col[beg + e + 12];
    int s7 = col[beg + e + 14];
    unsigned p0 = hs1[(size_t)s0 * 32 + u];
    unsigned p1 = hs1[(size_t)s1 * 32 + u];
    unsigned p2 = hs1[(size_t)s2 * 32 + u];
    unsigned p3 = hs1[(size_t)s3 * 32 + u];
    unsigned p4 = hs1[(size_t)s4 * 32 + u];
    unsigned p5 = hs1[(size_t)s5 * 32 + u];
    unsigned p6 = hs1[(size_t)s6 * 32 + u];
    unsigned p7 = hs1[(size_t)s7 * 32 + u];
    a0 += ((bf_lo(p0) + bf_lo(p1)) + (bf_lo(p2) + bf_lo(p3))) +
          ((bf_lo(p4) + bf_lo(p5)) + (bf_lo(p6) + bf_lo(p7)));
    a1 += ((bf_hi(p0) + bf_hi(p1)) + (bf_hi(p2) + bf_hi(p3))) +
          ((bf_hi(p4) + bf_hi(p5)) + (bf_hi(p6) + bf_hi(p7)));
  }
  // mid loop: 8 edges/iter (round-0 body)
  for (; e + 6 < cnt; e += 8) {
    int s0 = col[beg + e];
    int s1 = col[beg + e + 2];
    int s2 = col[beg + e + 4];
    int s3 = col[beg + e + 6];
    unsigned p0 = hs1[(size_t)s0 * 32 + u];
    unsigned p1 = hs1[(size_t)s1 * 32 + u];
    unsigned p2 = hs1[(size_t)s2 * 32 + u];
    unsigned p3 = hs1[(size_t)s3 * 32 + u];
    a0 += (bf_lo(p0) + bf_lo(p1)) + (bf_lo(p2) + bf_lo(p3));
    a1 += (bf_hi(p0) + bf_hi(p1)) + (bf_hi(p2) + bf_hi(p3));
  }
  for (; e < cnt; e += 2) {
    unsigned p = hs1[(size_t)col[beg + e] * 32 + u];
    a0 += bf_lo(p); a1 += bf_hi(p);
  }
  a0 += __shfl_xor(a0, 32);
  a1 += __shfl_xor(a1, 32);

  float dv = dinv[v];
  float2 bb = ((const float2*)b1)[u];
  float r0 = fmaxf(fmaf(a0, dv, bb.x), 0.f);  // relu(agg1[2u])
  float r1 = fmaxf(fmaf(a1, dv, bb.y), 0.f);  // relu(agg1[2u+1])

  // in-wave GEMM2: lane = (o=lane&15, q=lane>>4); k = q*16+i
  int o = lane & 15, q = lane >> 4;
  float part = 0.f;
#pragma unroll
  for (int i = 0; i < 16; i += 2) {
    int k = q * 16 + i;
    float e0 = __shfl(r0, k >> 1);        // channel k (even)
    float e1 = __shfl(r1, k >> 1);        // channel k+1 (odd)
    part = fmaf(e0, W2l[k * W2S + o], part);
    part = fmaf(e1, W2l[(k + 1) * W2S + o], part);
  }
  part += __shfl_xor(part, 16);
  part += __shfl_xor(part, 32);
  float h = part * dv;                     // hs2 channel o (lane<16 valid)
  float hnext = __shfl_xor(h, 1);
  if (lane < 16 && (lane & 1) == 0)
    hs2[(size_t)v * 8 + (o >> 1)] = pack2(h, hnext);
}

// ================= fused gather(16,bf16) + bias/ReLU + GEMM 16->2 =================
// wave per node; lane = (j=lane>>3 edge slot, p=lane&7 -> channels 2p,2p+1)

__global__ __launch_bounds__(BLK)
void k_gather16g3(const unsigned* __restrict__ hs2, const int* __restrict__ row_start,
                  const int* __restrict__ counts, const int* __restrict__ col,
                  const float* __restrict__ dinv, const float* __restrict__ b2,
                  const float* __restrict__ W3, float* __restrict__ hs3, int n) {
  int wave = threadIdx.x >> 6, lane = threadIdx.x & 63;
  int v = blockIdx.x * 4 + wave;
  if (v >= n) return;
  int j = lane >> 3, p = lane & 7;
  int beg = row_start[v], cnt = counts[v];

  float a0 = 0.f, a1 = 0.f;
  int e = j;
  for (; e + 8 < cnt; e += 16) {
    unsigned pk0 = hs2[(size_t)col[beg + e] * 8 + p];
    unsigned pk1 = hs2[(size_t)col[beg + e + 8] * 8 + p];
    a0 += bf_lo(pk0) + bf_lo(pk1);
    a1 += bf_hi(pk0) + bf_hi(pk1);
  }
  if (e < cnt) {
    unsigned pk = hs2[(size_t)col[beg + e] * 8 + p];
    a0 += bf_lo(pk); a1 += bf_hi(pk);
  }
  a0 += __shfl_xor(a0, 8);  a1 += __shfl_xor(a1, 8);
  a0 += __shfl_xor(a0, 16); a1 += __shfl_xor(a1, 16);
  a0 += __shfl_xor(a0, 32); a1 += __shfl_xor(a1, 32);

  unsigned ps = hs2[(size_t)v * 8 + p];  // self-loop
  a0 += bf_lo(ps); a1 += bf_hi(ps);

  float dv = dinv[v];
  float2 bb = ((const float2*)b2)[p];
  float r0 = fmaxf(fmaf(a0, dv, bb.x), 0.f);
  float r1 = fmaxf(fmaf(a1, dv, bb.y), 0.f);

  // GEMM3: out[o] = sum_k relu(agg2[k]) * W3[k][o]; channel 2i->r0@lane i, 2i+1->r1@lane i
  int o = lane & 1;
  float part = 0.f;
#pragma unroll
  for (int i = 0; i < 8; ++i) {
    float e0 = __shfl(r0, i);
    float e1 = __shfl(r1, i);
    part = fmaf(e0, W3[(2 * i) * 2 + o], part);
    part = fmaf(e1, W3[(2 * i + 1) * 2 + o], part);
  }
  if (lane < 2) hs3[(size_t)v * 2 + o] = part * dv;
}

// ================= final gather(2,fp32) + bias + log-softmax =================
// 4 lanes per node: 4 independent col->row chains in flight, quad shuffle-reduce.

__global__ __launch_bounds__(BLK)
void k_gather2_lsm(const float* __restrict__ hs3, const int* __restrict__ row_start,
                   const int* __restrict__ counts, const int* __restrict__ col,
                   const float* __restrict__ dinv, const float* __restrict__ b,
                   float* __restrict__ out, int n) {
  int t = threadIdx.x;
  int v = blockIdx.x * 64 + (t >> 2);
  int sl = t & 3;
  if (v >= n) return;
  const float2* h = (const float2*)hs3;
  int beg = row_start[v], cnt = counts[v];
  float a0 = 0.f, a1 = 0.f;
  int e = sl;
  for (; e + 4 < cnt; e += 8) {
    int c0 = col[beg + e];
    int c1 = col[beg + e + 4];
    float2 m0 = h[c0];
    float2 m1 = h[c1];
    a0 += m0.x + m1.x;
    a1 += m0.y + m1.y;
  }
  if (e < cnt) {
    float2 m = h[col[beg + e]];
    a0 += m.x; a1 += m.y;
  }
  a0 += __shfl_xor(a0, 1); a1 += __shfl_xor(a1, 1);
  a0 += __shfl_xor(a0, 2); a1 += __shfl_xor(a1, 2);
  if (sl == 0) {
    float2 self = h[v];
    a0 += self.x; a1 += self.y;
    float dv = dinv[v];
    a0 = fmaf(a0, dv, b[0]);
    a1 = fmaf(a1, dv, b[1]);
    float m = fmaxf(a0, a1);
    float l = m + logf(expf(a0 - m) + expf(a1 - m));
    ((float2*)out)[v] = make_float2(a0 - l, a1 - l);
  }
}

// ================= launch =================

extern "C" void kernel_launch(void* const* d_in, const int* in_sizes, int n_in,
                              void* d_out, int out_size, void* d_ws, size_t ws_size,
                              hipStream_t stream) {
  const float* x = (const float*)d_in[0];
  const int* edges = (const int*)d_in[1];   // int32
  const float* W1 = (const float*)d_in[2];
  const float* b1 = (const float*)d_in[3];
  const float* W2 = (const float*)d_in[4];
  const float* b2 = (const float*)d_in[5];
  const float* W3 = (const float*)d_in[6];
  const float* b3 = (const float*)d_in[7];
  float* out = (float*)d_out;

  const int N = in_sizes[0] / 165;
  const long long E = in_sizes[1] / 2;
  const int nbuk = (N + 255) >> 8;          // 782

  // workspace layout (16B-aligned chunks)
  char* w = (char*)d_ws;
  int* counts        = (int*)w;  w += (size_t)N * 4;
  int* row_start     = (int*)w;  w += (size_t)N * 4;
  float* dinv        = (float*)w; w += (size_t)N * 4;
  int* bucket_counts = (int*)w;  w += (NBUK_MAX + 4) * 4;
  int* bucket_start  = (int*)w;  w += (NBUK_MAX + 4) * 4;
  int* bucket_cursor = (int*)w;  w += (NBUK_MAX + 4) * 4;
  int* col           = (int*)w;  w += (size_t)E * 4;
  unsigned* hs1      = (unsigned*)w; w += (size_t)N * 32 * 4;   // bf16x2, 128B/row
  unsigned* hs2      = (unsigned*)w; w += (size_t)N * 8 * 4;    // bf16x2, 32B/row
  float* hs3         = (float*)w;                                // fp32, 8B/row
  int* tmp = (int*)hs1;  // aliases hs1: consumed by k_bfinal before k_gemm1 writes

  const int gN = (N + BLK - 1) / BLK;
  const int gW = (N + 3) / 4;
  const int NB_PART = 256;
  const long long chunk = (E + NB_PART - 1) / NB_PART;

  // ---- CSR build (binning) + dinv ----
  k_zero<<<(nbuk + BLK - 1) / BLK, BLK, 0, stream>>>(bucket_counts, nbuk);
  k_bcount<<<NB_PART, BLK, 0, stream>>>(edges, E, chunk, nbuk, bucket_counts);
  k_bscan<<<1, 1024, 0, stream>>>(bucket_counts, nbuk, bucket_start, bucket_cursor);
  k_bscatter<<<NB_PART, BLK, 0, stream>>>(edges, E, chunk, nbuk, bucket_cursor, tmp);
  k_bfinal<<<nbuk, BLK, 0, stream>>>(tmp, bucket_start, N, row_start, counts, dinv, col);

  // ---- layer 1: 165 -> 64 via fp16 MFMA (bf16 out), 128 rows/block ----
  k_gemm1<<<(N + G1R - 1) / G1R, BLK, 0, stream>>>(x, W1, dinv, hs1, N);

  // ---- layer 1 aggregate + layer 2 transform (fused) ----
  k_gather64g2<<<gW, BLK, 0, stream>>>(hs1, row_start, counts, col, dinv, b1, W2, hs2, N);

  // ---- layer 2 aggregate + layer 3 transform (fused) ----
  k_gather16g3<<<gW, BLK, 0, stream>>>(hs2, row_start, counts, col, dinv, b2, W3, hs3, N);

  // ---- layer 3 aggregate + bias + log-softmax ----
  k_gather2_lsm<<<(N + 63) / 64, BLK, 0, stream>>>(hs3, row_start, counts, col, dinv, b3, out, N);
}